// Round 5
// baseline (443.194 us; speedup 1.0000x reference)
//
#include <hip/hip_runtime.h>

#define SLOPE 0.01f

typedef float f32x4 __attribute__((ext_vector_type(4)));

// Weight pointers passed by value in the kernarg segment (160 B). The layer
// loop is fully unrolled -> h.w[L]/h.b[L] are compile-time kernarg offsets ->
// uniform pointers -> weights become scalar broadcast operands.
struct Half5 { const float* w[5]; const float* b[5]; };
struct WPtrs { Half5 logs; Half5 aff; };

// 5-layer 8->8 MLP, leaky ReLU after first 4 layers.
// w[L]: 64 fp32 row-major (out[j] += w[j*8+k] * x[k]); b[L]: 8 fp32.
__device__ __forceinline__ void mlp8(const Half5& h, const float x[8], float out[8]) {
    float a[8];
    #pragma unroll
    for (int j = 0; j < 8; ++j) a[j] = x[j];
    #pragma unroll
    for (int L = 0; L < 5; ++L) {
        const float* __restrict__ wl = h.w[L];
        const float* __restrict__ bl = h.b[L];
        float t[8];
        #pragma unroll
        for (int j = 0; j < 8; ++j) {
            float acc = bl[j];
            #pragma unroll
            for (int k = 0; k < 8; ++k)
                acc = fmaf(wl[j * 8 + k], a[k], acc);
            t[j] = acc;
        }
        #pragma unroll
        for (int j = 0; j < 8; ++j)
            a[j] = (L < 4) ? fmaxf(t[j], SLOPE * t[j]) : t[j];
    }
    #pragma unroll
    for (int j = 0; j < 8; ++j) out[j] = a[j];
}

// Measured ledger (clean kernel-only = dur_us - 313us harness fills):
//   R0 strided through-L2:               ~120 us
//   R1 strided + nt partial-line stores:  224 us (1.5x HBM write amp)
//   R2 LDS corner-turn stride-17, nt:    ~115 us (best; but all-b32 LDS ops)
//   R3 strided through-L2:               ~123 us
//   R4 stride-17 + divergent phase3:     ~126 us (SQ_LDS_BANK_CONFLICT 4M,
//                                         VALUBusy 55% -> LDS/VALU overhead)
// This version: row stride 20 floats (5 x f32x4, 16B-aligned) so ALL LDS ops
// are ds_{read,write}_b128 (14/thread vs ~56 b32). Row-read bank starts
// (80*l)%128 tile all 32 banks per 8 lanes -> near conflict-free. Cached
// loads (L3 serves ~half the input: FETCH 125MB < 256MB measured), nt
// full-line stores (clean WRITE_SIZE measured), uniform phase 3.
#define ROWF4 5   // f32x4 per row slot: 4 data + 1 pad

__global__ void __launch_bounds__(256)
coupling_kernel(const f32x4* __restrict__ z,   // 4 x float4 per row (16 fp32)
                WPtrs p,
                f32x4* __restrict__ out,
                int batch) {
    // Per-wave private chunk: 64 rows x 5 f32x4 = 5120 B; 4 waves = 20480 B.
    // No cross-wave sharing -> no __syncthreads(); same-wave LDS ordering is
    // enforced by compiler-inserted lgkmcnt waits.
    __shared__ f32x4 lds[4][64 * ROWF4];

    const int tid  = threadIdx.x;
    const int lane = tid & 63;
    const int wv   = tid >> 6;
    f32x4* __restrict__ L = lds[wv];

    const long long waveRow0 = (long long)blockIdx.x * 256 + (long long)wv * 64;
    const long long f4base   = waveRow0 * 4;
    const long long f4limit  = (long long)batch * 4;
    const int a = lane >> 2;          // row sub-index in corner turn
    const int b = lane & 3;           // f32x4 slot within a row

    // ---- Phase 1: fully-coalesced cached loads (1 KB/inst) -> LDS b128 ----
    #pragma unroll
    for (int i = 0; i < 4; ++i) {
        long long gi = f4base + (long long)(i * 64 + lane);
        f32x4 t = {0.f, 0.f, 0.f, 0.f};
        if (gi < f4limit) t = z[gi];
        L[(i * 16 + a) * ROWF4 + b] = t;            // ds_write_b128
    }

    // ---- Phase 2: each lane computes its own row out of LDS ----
    const long long row = waveRow0 + lane;
    if (row < batch) {
        const int r0 = lane * ROWF4;
        f32x4 q0 = L[r0 + 0], q1 = L[r0 + 1];       // zl  (ds_read_b128 x2)
        f32x4 q2 = L[r0 + 2], q3 = L[r0 + 3];       // zr

        float zl[8] = { q0.x, q0.y, q0.z, q0.w, q1.x, q1.y, q1.z, q1.w };
        float zr[8] = { q2.x, q2.y, q2.z, q2.w, q3.x, q3.y, q3.z, q3.w };

        float log_s[8], bb[8];
        mlp8(p.logs, zl, log_s);
        mlp8(p.aff,  zl, bb);

        float yr[8];
        #pragma unroll
        for (int k = 0; k < 8; ++k)
            yr[k] = fmaf(__expf(log_s[k]), zr[k], bb[k]);

        // Overwrite zr half; zl half untouched -> bit-exact passthrough.
        L[r0 + 2] = f32x4{ yr[0], yr[1], yr[2], yr[3] };   // ds_write_b128 x2
        L[r0 + 3] = f32x4{ yr[4], yr[5], yr[6], yr[7] };
    }

    // ---- Phase 3: uniform corner-turn out, nt full-line stores ----
    #pragma unroll
    for (int i = 0; i < 4; ++i) {
        long long gi = f4base + (long long)(i * 64 + lane);
        if (gi < f4limit) {
            f32x4 o = L[(i * 16 + a) * ROWF4 + b];  // ds_read_b128
            __builtin_nontemporal_store(o, out + gi);
        }
    }
}

extern "C" void kernel_launch(void* const* d_in, const int* in_sizes, int n_in,
                              void* d_out, int out_size, void* d_ws, size_t ws_size,
                              hipStream_t stream) {
    const int batch = in_sizes[0] / 16;

    WPtrs p;
    if (n_in >= 21) {
        // Lists flattened into 20 separate device arrays: pass pointers
        // directly as kernel args (no memcpy staging).
        for (int i = 0; i < 5; ++i) {
            p.logs.w[i] = (const float*)d_in[1 + i];    // ws_logs[i]: 8x8
            p.logs.b[i] = (const float*)d_in[6 + i];    // bs_logs[i]: 8
            p.aff.w[i]  = (const float*)d_in[11 + i];   // ws_b[i]:    8x8
            p.aff.b[i]  = (const float*)d_in[16 + i];   // bs_b[i]:    8
        }
    } else {
        const float* wl = (const float*)d_in[1];
        const float* bl = (const float*)d_in[2];
        const float* wv = (const float*)d_in[3];
        const float* bv = (const float*)d_in[4];
        for (int i = 0; i < 5; ++i) {
            p.logs.w[i] = wl + i * 64;
            p.logs.b[i] = bl + i * 8;
            p.aff.w[i]  = wv + i * 64;
            p.aff.b[i]  = bv + i * 8;
        }
    }

    int threads = 256;
    int blocks = (batch + threads - 1) / threads;
    coupling_kernel<<<blocks, threads, 0, stream>>>(
        (const f32x4*)d_in[0], p, (f32x4*)d_out, batch);
}

// Round 6
// 409.951 us; speedup vs baseline: 1.0811x; 1.0811x over previous
//
#include <hip/hip_runtime.h>

#define SLOPE 0.01f

typedef float f32x4 __attribute__((ext_vector_type(4)));
typedef float f32x2 __attribute__((ext_vector_type(2)));

// Weight pointers passed by value in the kernarg segment (160 B). The layer
// loop is fully unrolled -> h.w[L]/h.b[L] are compile-time kernarg offsets ->
// uniform pointers -> weight reads are scalar (s_load) broadcast operands.
struct Half5 { const float* w[5]; const float* b[5]; };
struct WPtrs { Half5 logs; Half5 aff; };

// 5-layer 8->8 MLP, leaky ReLU after first 4 layers.
// Packed-fp32 form: outputs paired (j,j+1) -> v_pk_fma_f32 / v_pk_max_f32
// (gfx950 full-rate packed fp32) halves MLP VALU instruction count.
//  - weight pair {w[j][k], w[j+1][k]}: both wave-uniform -> SGPR pair operand
//    (one constant-bus read, legal).
//  - activation splat {a[k],a[k]}: folds to op_sel on VOP3P.
//  - bias pair {b[j], b[j+1]}: memory-adjacent -> s_load_dwordx2.
__device__ __forceinline__ void mlp8(const Half5& h, const float x[8], float out[8]) {
    float a[8];
    #pragma unroll
    for (int j = 0; j < 8; ++j) a[j] = x[j];
    #pragma unroll
    for (int L = 0; L < 5; ++L) {
        const float* __restrict__ wl = h.w[L];
        const float* __restrict__ bl = h.b[L];
        f32x2 t2[4];
        #pragma unroll
        for (int j2 = 0; j2 < 4; ++j2)
            t2[j2] = f32x2{ bl[2 * j2], bl[2 * j2 + 1] };
        #pragma unroll
        for (int k = 0; k < 8; ++k) {
            const f32x2 xa = { a[k], a[k] };
            #pragma unroll
            for (int j2 = 0; j2 < 4; ++j2) {
                const f32x2 w2 = { wl[(2 * j2) * 8 + k], wl[(2 * j2 + 1) * 8 + k] };
                t2[j2] = __builtin_elementwise_fma(w2, xa, t2[j2]);
            }
        }
        #pragma unroll
        for (int j2 = 0; j2 < 4; ++j2) {
            f32x2 v = t2[j2];
            if (L < 4)
                v = __builtin_elementwise_max(v, v * SLOPE);   // leaky ReLU, packed
            a[2 * j2]     = v.x;
            a[2 * j2 + 1] = v.y;
        }
    }
    #pragma unroll
    for (int j = 0; j < 8; ++j) out[j] = a[j];
}

// Measured ledger (clean kernel-only = dur_us - 313us harness fills):
//   R0 strided through-L2:                ~120 us
//   R1 strided + nt partial-line stores:   224 us (1.5x HBM write amp)
//   R2 corner-turn s17, nt load+store:    ~115 us  <- best
//   R3 strided through-L2:                ~123 us
//   R4 s17, cached loads, divergent p3:   ~126 us
//   R5 s20 b128, cached loads, uniform:   ~130 us (b128 vs b32 LDS: no change
//      -> LDS ops never were the bottleneck; cached loads cost ~+12 us vs nt
//      despite halving FETCH_SIZE -> keep nt loads)
// This version: R5's b128 layout + R2's nt loads + packed-fp32 MLP + hoisted
// bounds checks.
#define ROWF4 5   // f32x4 slots per row: 4 data + 1 pad (bank spread)

__global__ void __launch_bounds__(256)
coupling_kernel(const f32x4* __restrict__ z,   // 4 x float4 per row (16 fp32)
                WPtrs p,
                f32x4* __restrict__ out,
                int batch) {
    // Per-wave private chunk: 64 rows x 5 f32x4 = 5120 B; 4 waves = 20480 B.
    // No cross-wave sharing -> no __syncthreads(); same-wave LDS ordering is
    // enforced by compiler-inserted lgkmcnt waits.
    __shared__ f32x4 lds[4][64 * ROWF4];

    const int tid  = threadIdx.x;
    const int lane = tid & 63;
    const int wv   = tid >> 6;
    f32x4* __restrict__ L = lds[wv];

    const long long waveRow0 = (long long)blockIdx.x * 256 + (long long)wv * 64;
    const long long f4base   = waveRow0 * 4;
    const long long f4limit  = (long long)batch * 4;
    const int a = lane >> 2;          // row sub-index in corner turn
    const int b = lane & 3;           // f32x4 slot within a row
    const bool full = ((long long)(blockIdx.x + 1) * 256) <= (long long)batch;

    // ---- Phase 1: coalesced nt loads (1 KB/inst) -> LDS ds_write_b128 ----
    if (full) {
        #pragma unroll
        for (int i = 0; i < 4; ++i) {
            f32x4 t = __builtin_nontemporal_load(z + f4base + (long long)(i * 64 + lane));
            L[(i * 16 + a) * ROWF4 + b] = t;
        }
    } else {
        #pragma unroll
        for (int i = 0; i < 4; ++i) {
            long long gi = f4base + (long long)(i * 64 + lane);
            f32x4 t = {0.f, 0.f, 0.f, 0.f};
            if (gi < f4limit) t = __builtin_nontemporal_load(z + gi);
            L[(i * 16 + a) * ROWF4 + b] = t;
        }
    }

    // ---- Phase 2: each lane computes its own row out of LDS ----
    if (full || (waveRow0 + lane) < batch) {
        const int r0 = lane * ROWF4;
        f32x4 q0 = L[r0 + 0], q1 = L[r0 + 1];       // zl  (ds_read_b128 x2)
        f32x4 q2 = L[r0 + 2], q3 = L[r0 + 3];       // zr

        float zl[8] = { q0.x, q0.y, q0.z, q0.w, q1.x, q1.y, q1.z, q1.w };
        float zr[8] = { q2.x, q2.y, q2.z, q2.w, q3.x, q3.y, q3.z, q3.w };

        float log_s[8], bb[8];
        mlp8(p.logs, zl, log_s);
        mlp8(p.aff,  zl, bb);

        float yr[8];
        #pragma unroll
        for (int k = 0; k < 8; ++k)
            yr[k] = fmaf(__expf(log_s[k]), zr[k], bb[k]);

        // Overwrite zr half; zl half untouched -> bit-exact passthrough.
        L[r0 + 2] = f32x4{ yr[0], yr[1], yr[2], yr[3] };
        L[r0 + 3] = f32x4{ yr[4], yr[5], yr[6], yr[7] };
    }

    // ---- Phase 3: uniform corner-turn out, nt full-line stores ----
    if (full) {
        #pragma unroll
        for (int i = 0; i < 4; ++i) {
            f32x4 o = L[(i * 16 + a) * ROWF4 + b];
            __builtin_nontemporal_store(o, out + f4base + (long long)(i * 64 + lane));
        }
    } else {
        #pragma unroll
        for (int i = 0; i < 4; ++i) {
            long long gi = f4base + (long long)(i * 64 + lane);
            if (gi < f4limit) {
                f32x4 o = L[(i * 16 + a) * ROWF4 + b];
                __builtin_nontemporal_store(o, out + gi);
            }
        }
    }
}

extern "C" void kernel_launch(void* const* d_in, const int* in_sizes, int n_in,
                              void* d_out, int out_size, void* d_ws, size_t ws_size,
                              hipStream_t stream) {
    const int batch = in_sizes[0] / 16;

    WPtrs p;
    if (n_in >= 21) {
        // Lists flattened into 20 separate device arrays: pass pointers
        // directly as kernel args (no memcpy staging).
        for (int i = 0; i < 5; ++i) {
            p.logs.w[i] = (const float*)d_in[1 + i];    // ws_logs[i]: 8x8
            p.logs.b[i] = (const float*)d_in[6 + i];    // bs_logs[i]: 8
            p.aff.w[i]  = (const float*)d_in[11 + i];   // ws_b[i]:    8x8
            p.aff.b[i]  = (const float*)d_in[16 + i];   // bs_b[i]:    8
        }
    } else {
        const float* wl = (const float*)d_in[1];
        const float* bl = (const float*)d_in[2];
        const float* wv = (const float*)d_in[3];
        const float* bv = (const float*)d_in[4];
        for (int i = 0; i < 5; ++i) {
            p.logs.w[i] = wl + i * 64;
            p.logs.b[i] = bl + i * 8;
            p.aff.w[i]  = wv + i * 64;
            p.aff.b[i]  = bv + i * 8;
        }
    }

    int threads = 256;
    int blocks = (batch + threads - 1) / threads;
    coupling_kernel<<<blocks, threads, 0, stream>>>(
        (const f32x4*)d_in[0], p, (f32x4*)d_out, batch);
}